// Round 14
// baseline (616.668 us; speedup 1.0000x reference)
//
#include <hip/hip_runtime.h>
#include <hip/hip_bf16.h>
#include <math.h>

// ---------------- common helpers ----------------

typedef short bf16x8 __attribute__((ext_vector_type(8)));
typedef float f32x4 __attribute__((ext_vector_type(4)));
typedef float f32x16 __attribute__((ext_vector_type(16)));

__device__ __host__ inline unsigned short f2bf(float f) {
    union { float f; unsigned u; } v; v.f = f;
    unsigned r = v.u + 0x7fff + ((v.u >> 16) & 1);   // RTNE
    return (unsigned short)(r >> 16);
}
__device__ inline unsigned short cvt_bf16(float f) {
    __hip_bfloat16 h = __float2bfloat16(f);
    return *reinterpret_cast<unsigned short*>(&h);
}
__device__ inline float bf2f(unsigned short b) {
    union { unsigned u; float f; } v; v.u = ((unsigned)b) << 16;
    return v.f;
}
// tanh(x) = 1 - 2/(exp(2x)+1); rcp approx well inside bf16 error budget.
__device__ inline float fast_tanh(float x) {
    float e = __expf(2.0f * x);
    return 1.0f - 2.0f * __builtin_amdgcn_rcpf(e + 1.0f);
}

// Safety: candidate set provably contains the true argmax iff DELTA >= 2*max_err.
// Measured values absmax = 0.0078125 (stable across 13 rounds) -> 2*err = 0.015625.
#define DELTA 0.018f
#define ITEM_CAP 16384

struct WLE { unsigned s, base, nc, pad; };

// rows-XOR swizzle, bijective within row strides 256/2048 B.
#define HSWZ(row, b) ((b) ^ (((row) & 15) << 4))

// ---------------- combined weight packing (zeroes both counters) ----------------
__global__ __launch_bounds__(256) void pack_all(
    const float* __restrict__ W2, const float* __restrict__ W3, const float* __restrict__ W4,
    unsigned short* __restrict__ W2p, unsigned short* __restrict__ W3p,
    unsigned short* __restrict__ W4p, unsigned* __restrict__ cnts)
{
    int tid = blockIdx.x * 256 + threadIdx.x;
    if (tid < 2) cnts[tid] = 0u;
    int blob = tid >> 6, lane = tid & 63;
    if (blob >= 2560) return;
    bf16x8 v;
    if (blob < 256) {
        // W2: 16x16x32 B-frag (HW-verified): lane holds col n=(l&15), k=8*((l>>4)&3)+e
        int nt = blob >> 2, kt = blob & 3;
        int n = nt * 16 + (lane & 15);
        int kbase = kt * 32 + ((lane >> 4) & 3) * 8;
        #pragma unroll
        for (int e = 0; e < 8; ++e) v[e] = (short)f2bf(W2[(size_t)(kbase + e) * 1024 + n]);
        *(bf16x8*)&W2p[(size_t)blob * 512 + lane * 8] = v;
    } else if (blob < 2304) {
        // W3: 32x32x16 B-frag (HW-verified): lane holds col n=(l&31), k=8*(l>>5)+e
        int lb = blob - 256;
        int nt = lb >> 6, kt = lb & 63;
        int n = nt * 32 + (lane & 31);
        int kbase = kt * 16 + (lane >> 5) * 8;
        #pragma unroll
        for (int e = 0; e < 8; ++e) v[e] = (short)f2bf(W3[(size_t)(kbase + e) * 1024 + n]);
        *(bf16x8*)&W3p[(size_t)lb * 512 + lane * 8] = v;
    } else {
        // W4: 16-frag, K=1024, N=128
        int lb = blob - 2304;
        int nt = lb >> 5, kt = lb & 31;
        int n = nt * 16 + (lane & 15);
        int kbase = kt * 32 + ((lane >> 4) & 3) * 8;
        #pragma unroll
        for (int e = 0; e < 8; ++e) v[e] = (short)f2bf(W4[(size_t)(kbase + e) * 128 + n]);
        *(bf16x8*)&W4p[(size_t)lb * 512 + lane * 8] = v;
    }
}

// ---------------- main fused MFMA kernel (round-6 core + fused scan; UNCHANGED) ----------------
__global__ __launch_bounds__(1024, 4) void qnet_mfma(
    const float* __restrict__ x, const float* __restrict__ actions,
    const float* __restrict__ W1, const float* __restrict__ b1,
    const float* __restrict__ b2, const float* __restrict__ b3,
    const float* __restrict__ b4,
    const float* __restrict__ W5, const float* __restrict__ b5,
    const unsigned short* __restrict__ W2p,
    const unsigned short* __restrict__ W3p,
    const unsigned short* __restrict__ W4p,
    float* __restrict__ values, float* __restrict__ out_actions,
    unsigned* __restrict__ cnts, WLE* __restrict__ wl,
    unsigned* __restrict__ items)
{
    __shared__ unsigned short h2[64 * 1024];  // 128 KB: h2, then h3 in-place
    __shared__ unsigned short hc[64 * 128];   // 16 KB: h1, then h4

    const int t = threadIdx.x;
    const int lane = t & 63;
    const int wave = t >> 6;       // 0..15
    const int p0 = blockIdx.x * 64;
    const int kb16 = (lane >> 4) * 16;   // 16x16x32 A k-subgroup byte offset
    const int kb32 = (lane >> 5) * 16;   // 32x32x16 A k-subgroup byte offset

    // ---- layer 1: h1 = tanh([x|a] @ W1 + b1) -> hc ----
    {
        int r = t >> 4;              // action index 0..63
        int c0 = (t & 15) * 8;
        const float* xs = &x[blockIdx.x * 5];
        const float* as = &actions[r * 4];
        float in[9] = { xs[0], xs[1], xs[2], xs[3], xs[4], as[0], as[1], as[2], as[3] };
        #pragma unroll
        for (int j = 0; j < 8; ++j) {
            int c = c0 + j;
            float acc = b1[c];
            #pragma unroll
            for (int k = 0; k < 9; ++k) acc += in[k] * W1[k * 128 + c];
            *(unsigned short*)((char*)hc + r * 256 + HSWZ(r, c * 2)) = cvt_bf16(fast_tanh(acc));
        }
    }
    __syncthreads();

    // ---- layer 2: 128 -> 1024. Wave owns 4 col-tiles; B shared across 4 row-tiles. ----
    {
        bf16x8 Af[4][4];
        #pragma unroll
        for (int rt = 0; rt < 4; ++rt)
            #pragma unroll
            for (int ks = 0; ks < 4; ++ks) {
                int row = rt * 16 + (lane & 15);
                Af[rt][ks] = *(const bf16x8*)((const char*)hc + row * 256 + HSWZ(row, ks * 64 + kb16));
            }
        #pragma unroll
        for (int j = 0; j < 4; ++j) {
            int nT = wave * 4 + j;
            float bv = b2[nT * 16 + (lane & 15)];
            f32x4 acc0 = (f32x4){ bv, bv, bv, bv };
            f32x4 acc1 = acc0, acc2 = acc0, acc3v = acc0;
            #pragma unroll
            for (int ks = 0; ks < 4; ++ks) {
                bf16x8 b = *(const bf16x8*)&W2p[((size_t)(nT * 4 + ks)) * 512 + lane * 8];
                acc0 = __builtin_amdgcn_mfma_f32_16x16x32_bf16(Af[0][ks], b, acc0, 0, 0, 0);
                acc1 = __builtin_amdgcn_mfma_f32_16x16x32_bf16(Af[1][ks], b, acc1, 0, 0, 0);
                acc2 = __builtin_amdgcn_mfma_f32_16x16x32_bf16(Af[2][ks], b, acc2, 0, 0, 0);
                acc3v = __builtin_amdgcn_mfma_f32_16x16x32_bf16(Af[3][ks], b, acc3v, 0, 0, 0);
            }
            int n = nT * 16 + (lane & 15);
            #pragma unroll
            for (int rr = 0; rr < 4; ++rr) {
                int m0 = (lane >> 4) * 4 + rr;
                *(unsigned short*)((char*)h2 + (m0 +  0) * 2048 + HSWZ(m0 +  0, n * 2)) = cvt_bf16(fast_tanh(acc0[rr]));
                *(unsigned short*)((char*)h2 + (m0 + 16) * 2048 + HSWZ(m0 + 16, n * 2)) = cvt_bf16(fast_tanh(acc1[rr]));
                *(unsigned short*)((char*)h2 + (m0 + 32) * 2048 + HSWZ(m0 + 32, n * 2)) = cvt_bf16(fast_tanh(acc2[rr]));
                *(unsigned short*)((char*)h2 + (m0 + 48) * 2048 + HSWZ(m0 + 48, n * 2)) = cvt_bf16(fast_tanh(acc3v[rr]));
            }
        }
    }
    __syncthreads();

    // ---- layer 3: 1024 -> 1024 via 32x32x16; acc register-resident (64 AGPR). ----
    f32x16 a00, a01, a10, a11;
    {
        float bv0 = b3[wave * 64 + (lane & 31)];
        float bv1 = b3[wave * 64 + 32 + (lane & 31)];
        #pragma unroll
        for (int i = 0; i < 16; ++i) { a00[i] = bv0; a10[i] = bv0; a01[i] = bv1; a11[i] = bv1; }
    }
    const int r0 = lane & 31, r1 = 32 + (lane & 31);
    {
        const unsigned short* bbase = &W3p[((size_t)(wave * 2) * 64) * 512 + lane * 8];
        #pragma unroll 2
        for (int kt = 0; kt < 64; ++kt) {
            bf16x8 A0 = *(const bf16x8*)((const char*)h2 + r0 * 2048 + HSWZ(r0, kt * 32 + kb32));
            bf16x8 A1 = *(const bf16x8*)((const char*)h2 + r1 * 2048 + HSWZ(r1, kt * 32 + kb32));
            bf16x8 B0 = *(const bf16x8*)(bbase + (size_t)kt * 512);
            bf16x8 B1 = *(const bf16x8*)(bbase + (size_t)(64 + kt) * 512);
            a00 = __builtin_amdgcn_mfma_f32_32x32x16_bf16(A0, B0, a00, 0, 0, 0);
            a10 = __builtin_amdgcn_mfma_f32_32x32x16_bf16(A1, B0, a10, 0, 0, 0);
            a01 = __builtin_amdgcn_mfma_f32_32x32x16_bf16(A0, B1, a01, 0, 0, 0);
            a11 = __builtin_amdgcn_mfma_f32_32x32x16_bf16(A1, B1, a11, 0, 0, 0);
        }
    }
    __syncthreads();

    // ---- h3 = tanh(acc3) -> h2 IN PLACE ----
    {
        int c0l = wave * 64 + (lane & 31);
        #pragma unroll
        for (int r = 0; r < 16; ++r) {
            int row = (r & 3) + 8 * (r >> 2) + 4 * (lane >> 5);   // 0..31
            int rowB = row + 32;
            *(unsigned short*)((char*)h2 + row  * 2048 + HSWZ(row,  c0l * 2)) = cvt_bf16(fast_tanh(a00[r]));
            *(unsigned short*)((char*)h2 + rowB * 2048 + HSWZ(rowB, c0l * 2)) = cvt_bf16(fast_tanh(a10[r]));
            *(unsigned short*)((char*)h2 + row  * 2048 + HSWZ(row,  (c0l + 32) * 2)) = cvt_bf16(fast_tanh(a01[r]));
            *(unsigned short*)((char*)h2 + rowB * 2048 + HSWZ(rowB, (c0l + 32) * 2)) = cvt_bf16(fast_tanh(a11[r]));
        }
    }
    __syncthreads();

    // ---- layer 4: 1024 -> 128 ----
    {
        const int ct = wave & 7, rtp = wave >> 3;
        const int rowA = rtp * 32 + (lane & 15);
        const int rowB = rowA + 16;
        float bv = b4[ct * 16 + (lane & 15)];
        f32x4 acc4a = (f32x4){ bv, bv, bv, bv };
        f32x4 acc4b = acc4a;
        #pragma unroll 4
        for (int k32 = 0; k32 < 32; ++k32) {
            bf16x8 B = *(const bf16x8*)&W4p[((size_t)(ct * 32 + k32)) * 512 + lane * 8];
            bf16x8 aA = *(const bf16x8*)((const char*)h2 + rowA * 2048 + HSWZ(rowA, k32 * 64 + kb16));
            bf16x8 aB = *(const bf16x8*)((const char*)h2 + rowB * 2048 + HSWZ(rowB, k32 * 64 + kb16));
            acc4a = __builtin_amdgcn_mfma_f32_16x16x32_bf16(aA, B, acc4a, 0, 0, 0);
            acc4b = __builtin_amdgcn_mfma_f32_16x16x32_bf16(aB, B, acc4b, 0, 0, 0);
        }
        int n = ct * 16 + (lane & 15);
        #pragma unroll
        for (int rr = 0; rr < 4; ++rr) {
            int mA = rtp * 32 + (lane >> 4) * 4 + rr;
            int mB = mA + 16;
            *(unsigned short*)((char*)hc + mA * 256 + HSWZ(mA, n * 2)) = cvt_bf16(fast_tanh(acc4a[rr]));
            *(unsigned short*)((char*)hc + mB * 256 + HSWZ(mB, n * 2)) = cvt_bf16(fast_tanh(acc4b[rr]));
        }
    }
    __syncthreads();

    // ---- layer 5 ----
    float* vbuf = (float*)&h2[0];
    {
        int r = t >> 4, g = t & 15;
        float part = 0.0f;
        #pragma unroll
        for (int j = 0; j < 8; ++j) {
            int cidx = g * 8 + j;
            unsigned short hb = *(const unsigned short*)((const char*)hc + r * 256 + HSWZ(r, cidx * 2));
            part += bf2f(hb) * W5[cidx];
        }
        part += __shfl_down(part, 8);
        part += __shfl_down(part, 4);
        part += __shfl_down(part, 2);
        part += __shfl_down(part, 1);
        if (g == 0) {
            float val = part + b5[0];
            values[p0 + r] = val;
            vbuf[r] = val;
        }
    }
    __syncthreads();

    // ---- fused scan: default argmax-gather + worklist emission (wave 0) ----
    if (t < 64) {
        float myv = vbuf[t];
        float v = myv; int idx = t;
        #pragma unroll
        for (int off = 32; off; off >>= 1) {
            float ov = __shfl_down(v, off);
            int oi = __shfl_down(idx, off);
            if (ov > v || (ov == v && oi < idx)) { v = ov; idx = oi; }
        }
        float vm = __shfl(v, 0);
        int best = __shfl(idx, 0);
        if (t < 4) out_actions[blockIdx.x * 4 + t] = actions[best * 4 + t];
        unsigned long long mask = __ballot(myv >= vm - DELTA);
        int nc = __popcll(mask);
        if (nc > 1) {
            unsigned base = 0;
            if (t == 0) base = atomicAdd(&cnts[1], (unsigned)nc);
            base = (unsigned)__shfl((int)base, 0);
            if (base + (unsigned)nc <= (unsigned)ITEM_CAP) {
                if (t == 0) {
                    unsigned slot = atomicAdd(&cnts[0], 1u);
                    wl[slot].s = blockIdx.x; wl[slot].base = base; wl[slot].nc = (unsigned)nc;
                }
                if (myv >= vm - DELTA) {
                    int rank = __popcll(mask & ((1ull << t) - 1ull));
                    items[base + rank] = ((unsigned)blockIdx.x << 6) | (unsigned)t;
                }
            }
        }
    }
}

// ---------------- exact evaluator: 16 items per batch, 512 threads, float4 loads ----------------
// Row-split halves (t<256 -> rows 0-7, t>=256 -> rows 8-15) keep float4 weight
// loads; the second half's identical W-addresses hit L1. Per-item weight
// streaming is HALF of the 8-item version. LDS rows padded (+4 floats) to
// spread the 8-row same-column broadcast across banks.
__global__ __launch_bounds__(512) void fixup_eval(
    const float* __restrict__ x, const float* __restrict__ actions,
    const float* __restrict__ W1, const float* __restrict__ b1,
    const float* __restrict__ W2, const float* __restrict__ b2,
    const float* __restrict__ W3, const float* __restrict__ b3,
    const float* __restrict__ W4, const float* __restrict__ b4,
    const float* __restrict__ W5, const float* __restrict__ b5,
    const unsigned* __restrict__ cnts, const unsigned* __restrict__ items,
    float* __restrict__ vexact)
{
    __shared__ float h1s[16][132];    //  8.25 KB (padded)
    __shared__ float h2s[16][1028];   // 64.25 KB (padded)
    __shared__ float h3s[16][1028];   // 64.25 KB (padded)
    __shared__ float h4s[16][132];    //  8.25 KB (padded)
    __shared__ float xin[16][5];
    __shared__ float ain[16][4];

    const int t = threadIdx.x;
    const int rg = t >> 8;            // row-group 0/1 -> rows rg*8..+8
    const int cb1024 = (t & 255) * 4; // 4-col slice of 1024
    int n = (int)cnts[1]; if (n > ITEM_CAP) n = ITEM_CAP;
    int nb = (n + 15) >> 4;
    for (int b = blockIdx.x; b < nb; b += gridDim.x) {
        if (t < 16) {
            int idx = b * 16 + t;
            unsigned it = items[(idx < n) ? idx : (b * 16)];
            int s = (int)((it >> 6) & 2047), a = (int)(it & 63);
            #pragma unroll
            for (int k = 0; k < 5; ++k) xin[t][k] = x[s * 5 + k];
            #pragma unroll
            for (int k = 0; k < 4; ++k) ain[t][k] = actions[a * 4 + k];
        }
        __syncthreads();
        // L1: 16 rows x 128 cols; r = t>>5, cols (t&31)*4..+4
        {
            int r = t >> 5, cb = (t & 31) * 4;
            #pragma unroll
            for (int j = 0; j < 4; ++j) {
                int c = cb + j;
                float acc = b1[c];
                #pragma unroll
                for (int k = 0; k < 5; ++k) acc += xin[r][k] * W1[k * 128 + c];
                #pragma unroll
                for (int k = 0; k < 4; ++k) acc += ain[r][k] * W1[(5 + k) * 128 + c];
                h1s[r][c] = tanhf(acc);
            }
        }
        __syncthreads();
        // L2: 128 -> 1024. Thread: 4 cols (cb1024), 8 rows (rg half). float4 W2.
        {
            float acc[8][4];
            float4 bv = *(const float4*)&b2[cb1024];
            #pragma unroll
            for (int r = 0; r < 8; ++r) { acc[r][0]=bv.x; acc[r][1]=bv.y; acc[r][2]=bv.z; acc[r][3]=bv.w; }
            for (int k = 0; k < 128; ++k) {
                float4 w = *(const float4*)&W2[k * 1024 + cb1024];
                #pragma unroll
                for (int r = 0; r < 8; ++r) {
                    float hv = h1s[rg * 8 + r][k];
                    acc[r][0] += hv * w.x; acc[r][1] += hv * w.y;
                    acc[r][2] += hv * w.z; acc[r][3] += hv * w.w;
                }
            }
            #pragma unroll
            for (int r = 0; r < 8; ++r)
                #pragma unroll
                for (int j = 0; j < 4; ++j)
                    h2s[rg * 8 + r][cb1024 + j] = tanhf(acc[r][j]);
        }
        __syncthreads();
        // L3: 1024 -> 1024. Same decomposition; float4 W3 (L1-deduped across halves).
        {
            float acc[8][4];
            float4 bv = *(const float4*)&b3[cb1024];
            #pragma unroll
            for (int r = 0; r < 8; ++r) { acc[r][0]=bv.x; acc[r][1]=bv.y; acc[r][2]=bv.z; acc[r][3]=bv.w; }
            for (int k = 0; k < 1024; ++k) {
                float4 w = *(const float4*)&W3[k * 1024 + cb1024];
                #pragma unroll
                for (int r = 0; r < 8; ++r) {
                    float hv = h2s[rg * 8 + r][k];
                    acc[r][0] += hv * w.x; acc[r][1] += hv * w.y;
                    acc[r][2] += hv * w.z; acc[r][3] += hv * w.w;
                }
            }
            #pragma unroll
            for (int r = 0; r < 8; ++r)
                #pragma unroll
                for (int j = 0; j < 4; ++j)
                    h3s[rg * 8 + r][cb1024 + j] = tanhf(acc[r][j]);
        }
        __syncthreads();
        // L4: 1024 -> 128. r = t>>5 (16 rows), cols (t&31)*4..+4; float4 W4.
        {
            int r = t >> 5, cb = (t & 31) * 4;
            float acc[4];
            float4 bv = *(const float4*)&b4[cb];
            acc[0]=bv.x; acc[1]=bv.y; acc[2]=bv.z; acc[3]=bv.w;
            for (int k = 0; k < 1024; ++k) {
                float4 w = *(const float4*)&W4[k * 128 + cb];
                float hv = h3s[r][k];
                acc[0] += hv * w.x; acc[1] += hv * w.y; acc[2] += hv * w.z; acc[3] += hv * w.w;
            }
            #pragma unroll
            for (int j = 0; j < 4; ++j) h4s[r][cb + j] = tanhf(acc[j]);
        }
        __syncthreads();
        // L5: r = t>>5, g = t&31 (4 cols each); reduce within the 32-lane group.
        {
            int r = t >> 5, g = t & 31;
            float part = 0.0f;
            #pragma unroll
            for (int j = 0; j < 4; ++j) part += h4s[r][g * 4 + j] * W5[g * 4 + j];
            part += __shfl_down(part, 16);
            part += __shfl_down(part, 8);
            part += __shfl_down(part, 4);
            part += __shfl_down(part, 2);
            part += __shfl_down(part, 1);
            if (g == 0) {
                int idx = b * 16 + r;
                if (idx < n) vexact[idx] = part + b5[0];
            }
        }
        __syncthreads();
    }
}

// ---------------- final per-state first-max over exact candidate values ----------------
__global__ __launch_bounds__(256) void finalize_argmax(
    const unsigned* __restrict__ cnts, const WLE* __restrict__ wl,
    const unsigned* __restrict__ items, const float* __restrict__ vexact,
    const float* __restrict__ actions, float* __restrict__ out_actions)
{
    int gw = (blockIdx.x * 256 + threadIdx.x) >> 6;
    int lane = threadIdx.x & 63;
    int nwl = (int)cnts[0]; if (nwl > 2048) nwl = 2048;
    if (gw >= nwl) return;
    unsigned s = wl[gw].s, base = wl[gw].base, nc = wl[gw].nc;
    float v = (lane < (int)nc) ? vexact[base + lane] : -3.0e38f;
    int idx = lane;
    #pragma unroll
    for (int off = 32; off; off >>= 1) {
        float ov = __shfl_down(v, off);
        int oi = __shfl_down(idx, off);
        if (ov > v || (ov == v && oi < idx)) { v = ov; idx = oi; }
    }
    int i0 = __shfl(idx, 0);   // items ascend in action order -> first-max
    int a = (int)(items[base + i0] & 63);
    if (lane < 4) out_actions[s * 4 + lane] = actions[a * 4 + lane];
}

// ---------------- fp32 fallback (ws too small) ----------------
#define TR 16
__global__ __launch_bounds__(256) void qnet_fused(
    const float* __restrict__ x, const float* __restrict__ actions,
    const float* __restrict__ W1, const float* __restrict__ b1,
    const float* __restrict__ W2, const float* __restrict__ b2,
    const float* __restrict__ W3, const float* __restrict__ b3,
    const float* __restrict__ W4, const float* __restrict__ b4,
    const float* __restrict__ W5, const float* __restrict__ b5,
    float* __restrict__ values)
{
    __shared__ float h_small[TR][128];
    __shared__ float hA[TR][1024];
    __shared__ float hB[TR][1024];
    const int t = threadIdx.x;
    const int p0 = blockIdx.x * TR;
    for (int i = t; i < TR * 128; i += 256) {
        int r = i >> 7, c = i & 127;
        int p = p0 + r;
        int bidx = p >> 6, aidx = p & 63;
        float acc = b1[c];
        for (int k = 0; k < 5; ++k) acc += x[bidx * 5 + k] * W1[k * 128 + c];
        for (int k = 0; k < 4; ++k) acc += actions[aidx * 4 + k] * W1[(5 + k) * 128 + c];
        h_small[r][c] = tanhf(acc);
    }
    __syncthreads();
    {
        const int c0 = t * 4;
        float4 bias = *(const float4*)&b2[c0];
        float acc[TR][4];
        for (int r = 0; r < TR; ++r) { acc[r][0]=bias.x; acc[r][1]=bias.y; acc[r][2]=bias.z; acc[r][3]=bias.w; }
        for (int k = 0; k < 128; k += 4) {
            float4 w0 = *(const float4*)&W2[(k+0)*1024+c0];
            float4 w1 = *(const float4*)&W2[(k+1)*1024+c0];
            float4 w2 = *(const float4*)&W2[(k+2)*1024+c0];
            float4 w3 = *(const float4*)&W2[(k+3)*1024+c0];
            for (int r = 0; r < TR; ++r) {
                float4 hv = *(const float4*)&h_small[r][k];
                acc[r][0] += hv.x*w0.x + hv.y*w1.x + hv.z*w2.x + hv.w*w3.x;
                acc[r][1] += hv.x*w0.y + hv.y*w1.y + hv.z*w2.y + hv.w*w3.y;
                acc[r][2] += hv.x*w0.z + hv.y*w1.z + hv.z*w2.z + hv.w*w3.z;
                acc[r][3] += hv.x*w0.w + hv.y*w1.w + hv.z*w2.w + hv.w*w3.w;
            }
        }
        for (int r = 0; r < TR; ++r) {
            hA[r][c0+0]=tanhf(acc[r][0]); hA[r][c0+1]=tanhf(acc[r][1]);
            hA[r][c0+2]=tanhf(acc[r][2]); hA[r][c0+3]=tanhf(acc[r][3]);
        }
    }
    __syncthreads();
    {
        const int c0 = t * 4;
        float4 bias = *(const float4*)&b3[c0];
        float acc[TR][4];
        for (int r = 0; r < TR; ++r) { acc[r][0]=bias.x; acc[r][1]=bias.y; acc[r][2]=bias.z; acc[r][3]=bias.w; }
        for (int k = 0; k < 1024; k += 4) {
            float4 w0 = *(const float4*)&W3[(k+0)*1024+c0];
            float4 w1 = *(const float4*)&W3[(k+1)*1024+c0];
            float4 w2 = *(const float4*)&W3[(k+2)*1024+c0];
            float4 w3 = *(const float4*)&W3[(k+3)*1024+c0];
            for (int r = 0; r < TR; ++r) {
                float4 hv = *(const float4*)&hA[r][k];
                acc[r][0] += hv.x*w0.x + hv.y*w1.x + hv.z*w2.x + hv.w*w3.x;
                acc[r][1] += hv.x*w0.y + hv.y*w1.y + hv.z*w2.y + hv.w*w3.y;
                acc[r][2] += hv.x*w0.z + hv.y*w1.z + hv.z*w2.z + hv.w*w3.z;
                acc[r][3] += hv.x*w0.w + hv.y*w1.w + hv.z*w2.w + hv.w*w3.w;
            }
        }
        for (int r = 0; r < TR; ++r) {
            hB[r][c0+0]=tanhf(acc[r][0]); hB[r][c0+1]=tanhf(acc[r][1]);
            hB[r][c0+2]=tanhf(acc[r][2]); hB[r][c0+3]=tanhf(acc[r][3]);
        }
    }
    __syncthreads();
    {
        const int c = t & 127;
        const int rh = t >> 7;
        float acc[8];
        float bias = b4[c];
        for (int r = 0; r < 8; ++r) acc[r] = bias;
        for (int k = 0; k < 1024; k += 4) {
            float w0 = W4[(k+0)*128+c], w1 = W4[(k+1)*128+c];
            float w2 = W4[(k+2)*128+c], w3 = W4[(k+3)*128+c];
            for (int r = 0; r < 8; ++r) {
                float4 hv = *(const float4*)&hB[rh*8+r][k];
                acc[r] += hv.x*w0 + hv.y*w1 + hv.z*w2 + hv.w*w3;
            }
        }
        for (int r = 0; r < 8; ++r) h_small[rh*8+r][c] = tanhf(acc[r]);
    }
    __syncthreads();
    if (t < TR) {
        float acc = b5[0];
        for (int k = 0; k < 128; k += 4) {
            float4 hv = *(const float4*)&h_small[t][k];
            float4 wv = *(const float4*)&W5[k];
            acc += hv.x*wv.x + hv.y*wv.y + hv.z*wv.z + hv.w*wv.w;
        }
        values[p0 + t] = acc;
    }
}

__global__ __launch_bounds__(256) void argmax_gather(
    const float* __restrict__ values, const float* __restrict__ actions,
    float* __restrict__ out_actions)
{
    const int wave = threadIdx.x >> 6;
    const int lane = threadIdx.x & 63;
    const int state = blockIdx.x * (blockDim.x >> 6) + wave;
    float v = values[state * 64 + lane];
    int idx = lane;
    for (int off = 32; off; off >>= 1) {
        float ov = __shfl_down(v, off);
        int oi = __shfl_down(idx, off);
        if (ov > v || (ov == v && oi < idx)) { v = ov; idx = oi; }
    }
    idx = __shfl(idx, 0);
    if (lane < 4) out_actions[state * 4 + lane] = actions[idx * 4 + lane];
}

// ---------------- launcher ----------------
extern "C" void kernel_launch(void* const* d_in, const int* in_sizes, int n_in,
                              void* d_out, int out_size, void* d_ws, size_t ws_size,
                              hipStream_t stream) {
    const float* x       = (const float*)d_in[0];
    const float* actions = (const float*)d_in[1];
    const float* W1 = (const float*)d_in[2];  const float* b1 = (const float*)d_in[3];
    const float* W2 = (const float*)d_in[4];  const float* b2 = (const float*)d_in[5];
    const float* W3 = (const float*)d_in[6];  const float* b3 = (const float*)d_in[7];
    const float* W4 = (const float*)d_in[8];  const float* b4 = (const float*)d_in[9];
    const float* W5 = (const float*)d_in[10]; const float* b5 = (const float*)d_in[11];

    float* out_actions = (float*)d_out;              // [2048,4]
    float* values      = (float*)d_out + 2048 * 4;   // [2048,64]

    const size_t nW2 = 128 * 1024, nW3 = 1024 * 1024, nW4 = 1024 * 128;
    const size_t wbytes = (nW2 + nW3 + nW4) * sizeof(unsigned short);   // 2621440
    const size_t need = wbytes + 16 + 2048 * sizeof(WLE) + ITEM_CAP * 4 + ITEM_CAP * 4;

    if (ws_size >= need) {
        unsigned short* W2p = (unsigned short*)d_ws;
        unsigned short* W3p = W2p + nW2;
        unsigned short* W4p = W3p + nW3;
        char* p = (char*)d_ws + wbytes;
        unsigned* cnts = (unsigned*)p;                 p += 16;
        WLE* wl = (WLE*)p;                             p += 2048 * sizeof(WLE);
        unsigned* items = (unsigned*)p;                p += ITEM_CAP * 4;
        float* vexact = (float*)p;

        pack_all<<<640, 256, 0, stream>>>(W2, W3, W4, W2p, W3p, W4p, cnts);
        qnet_mfma<<<2048, 1024, 0, stream>>>(x, actions, W1, b1, b2, b3, b4, W5, b5,
                                             W2p, W3p, W4p, values, out_actions,
                                             cnts, wl, items);
        fixup_eval<<<512, 512, 0, stream>>>(x, actions, W1, b1, W2, b2, W3, b3,
                                            W4, b4, W5, b5, cnts, items, vexact);
        finalize_argmax<<<512, 256, 0, stream>>>(cnts, wl, items, vexact,
                                                 actions, out_actions);
    } else {
        qnet_fused<<<2048 * 64 / TR, 256, 0, stream>>>(x, actions, W1, b1, W2, b2, W3, b3,
                                                       W4, b4, W5, b5, values);
        argmax_gather<<<2048 / 4, 256, 0, stream>>>(values, actions, out_actions);
    }
}

// Round 15
// 593.728 us; speedup vs baseline: 1.0386x; 1.0386x over previous
//
#include <hip/hip_runtime.h>
#include <hip/hip_bf16.h>
#include <math.h>

// ---------------- common helpers ----------------

typedef short bf16x8 __attribute__((ext_vector_type(8)));
typedef float f32x4 __attribute__((ext_vector_type(4)));
typedef float f32x16 __attribute__((ext_vector_type(16)));

__device__ __host__ inline unsigned short f2bf(float f) {
    union { float f; unsigned u; } v; v.f = f;
    unsigned r = v.u + 0x7fff + ((v.u >> 16) & 1);   // RTNE
    return (unsigned short)(r >> 16);
}
__device__ inline unsigned short cvt_bf16(float f) {
    __hip_bfloat16 h = __float2bfloat16(f);
    return *reinterpret_cast<unsigned short*>(&h);
}
__device__ inline float bf2f(unsigned short b) {
    union { unsigned u; float f; } v; v.u = ((unsigned)b) << 16;
    return v.f;
}
// tanh(x) = 1 - 2/(exp(2x)+1); rcp approx well inside bf16 error budget.
__device__ inline float fast_tanh(float x) {
    float e = __expf(2.0f * x);
    return 1.0f - 2.0f * __builtin_amdgcn_rcpf(e + 1.0f);
}

// Safety: candidate set provably contains the true argmax iff DELTA >= 2*max_err.
// Measured values absmax = 0.0078125 (stable across 14 rounds) -> 2*err = 0.015625.
#define DELTA 0.018f
#define ITEM_CAP 16384

struct WLE { unsigned s, base, nc, pad; };

// rows-XOR swizzle, bijective within row strides 256/2048 B.
#define HSWZ(row, b) ((b) ^ (((row) & 15) << 4))

// ---------------- combined weight packing (zeroes both counters) ----------------
__global__ __launch_bounds__(256) void pack_all(
    const float* __restrict__ W2, const float* __restrict__ W3, const float* __restrict__ W4,
    unsigned short* __restrict__ W2p, unsigned short* __restrict__ W3p,
    unsigned short* __restrict__ W4p, unsigned* __restrict__ cnts)
{
    int tid = blockIdx.x * 256 + threadIdx.x;
    if (tid < 2) cnts[tid] = 0u;
    int blob = tid >> 6, lane = tid & 63;
    if (blob >= 2560) return;
    bf16x8 v;
    if (blob < 256) {
        // W2: 16x16x32 B-frag (HW-verified): lane holds col n=(l&15), k=8*((l>>4)&3)+e
        int nt = blob >> 2, kt = blob & 3;
        int n = nt * 16 + (lane & 15);
        int kbase = kt * 32 + ((lane >> 4) & 3) * 8;
        #pragma unroll
        for (int e = 0; e < 8; ++e) v[e] = (short)f2bf(W2[(size_t)(kbase + e) * 1024 + n]);
        *(bf16x8*)&W2p[(size_t)blob * 512 + lane * 8] = v;
    } else if (blob < 2304) {
        // W3: 32x32x16 B-frag (HW-verified): lane holds col n=(l&31), k=8*(l>>5)+e
        int lb = blob - 256;
        int nt = lb >> 6, kt = lb & 63;
        int n = nt * 32 + (lane & 31);
        int kbase = kt * 16 + (lane >> 5) * 8;
        #pragma unroll
        for (int e = 0; e < 8; ++e) v[e] = (short)f2bf(W3[(size_t)(kbase + e) * 1024 + n]);
        *(bf16x8*)&W3p[(size_t)lb * 512 + lane * 8] = v;
    } else {
        // W4: 16-frag, K=1024, N=128
        int lb = blob - 2304;
        int nt = lb >> 5, kt = lb & 31;
        int n = nt * 16 + (lane & 15);
        int kbase = kt * 32 + ((lane >> 4) & 3) * 8;
        #pragma unroll
        for (int e = 0; e < 8; ++e) v[e] = (short)f2bf(W4[(size_t)(kbase + e) * 128 + n]);
        *(bf16x8*)&W4p[(size_t)lb * 512 + lane * 8] = v;
    }
}

// ---------------- main fused MFMA kernel (round-6 core + fused scan) ----------------
__global__ __launch_bounds__(1024, 4) void qnet_mfma(
    const float* __restrict__ x, const float* __restrict__ actions,
    const float* __restrict__ W1, const float* __restrict__ b1,
    const float* __restrict__ b2, const float* __restrict__ b3,
    const float* __restrict__ b4,
    const float* __restrict__ W5, const float* __restrict__ b5,
    const unsigned short* __restrict__ W2p,
    const unsigned short* __restrict__ W3p,
    const unsigned short* __restrict__ W4p,
    float* __restrict__ values, float* __restrict__ out_actions,
    unsigned* __restrict__ cnts, WLE* __restrict__ wl,
    unsigned* __restrict__ items)
{
    __shared__ unsigned short h2[64 * 1024];  // 128 KB: h2, then h3 in-place
    __shared__ unsigned short hc[64 * 128];   // 16 KB: h1, then h4

    const int t = threadIdx.x;
    const int lane = t & 63;
    const int wave = t >> 6;       // 0..15
    const int p0 = blockIdx.x * 64;
    const int kb16 = (lane >> 4) * 16;   // 16x16x32 A k-subgroup byte offset
    const int kb32 = (lane >> 5) * 16;   // 32x32x16 A k-subgroup byte offset

    // ---- layer 1: h1 = tanh([x|a] @ W1 + b1) -> hc ----
    {
        int r = t >> 4;              // action index 0..63
        int c0 = (t & 15) * 8;
        const float* xs = &x[blockIdx.x * 5];
        const float* as = &actions[r * 4];
        float in[9] = { xs[0], xs[1], xs[2], xs[3], xs[4], as[0], as[1], as[2], as[3] };
        #pragma unroll
        for (int j = 0; j < 8; ++j) {
            int c = c0 + j;
            float acc = b1[c];
            #pragma unroll
            for (int k = 0; k < 9; ++k) acc += in[k] * W1[k * 128 + c];
            *(unsigned short*)((char*)hc + r * 256 + HSWZ(r, c * 2)) = cvt_bf16(fast_tanh(acc));
        }
    }
    __syncthreads();

    // ---- layer 2: 128 -> 1024. Wave owns 4 col-tiles; B shared across 4 row-tiles. ----
    {
        bf16x8 Af[4][4];
        #pragma unroll
        for (int rt = 0; rt < 4; ++rt)
            #pragma unroll
            for (int ks = 0; ks < 4; ++ks) {
                int row = rt * 16 + (lane & 15);
                Af[rt][ks] = *(const bf16x8*)((const char*)hc + row * 256 + HSWZ(row, ks * 64 + kb16));
            }
        #pragma unroll
        for (int j = 0; j < 4; ++j) {
            int nT = wave * 4 + j;
            float bv = b2[nT * 16 + (lane & 15)];
            f32x4 acc0 = (f32x4){ bv, bv, bv, bv };
            f32x4 acc1 = acc0, acc2 = acc0, acc3v = acc0;
            #pragma unroll
            for (int ks = 0; ks < 4; ++ks) {
                bf16x8 b = *(const bf16x8*)&W2p[((size_t)(nT * 4 + ks)) * 512 + lane * 8];
                acc0 = __builtin_amdgcn_mfma_f32_16x16x32_bf16(Af[0][ks], b, acc0, 0, 0, 0);
                acc1 = __builtin_amdgcn_mfma_f32_16x16x32_bf16(Af[1][ks], b, acc1, 0, 0, 0);
                acc2 = __builtin_amdgcn_mfma_f32_16x16x32_bf16(Af[2][ks], b, acc2, 0, 0, 0);
                acc3v = __builtin_amdgcn_mfma_f32_16x16x32_bf16(Af[3][ks], b, acc3v, 0, 0, 0);
            }
            int n = nT * 16 + (lane & 15);
            #pragma unroll
            for (int rr = 0; rr < 4; ++rr) {
                int m0 = (lane >> 4) * 4 + rr;
                *(unsigned short*)((char*)h2 + (m0 +  0) * 2048 + HSWZ(m0 +  0, n * 2)) = cvt_bf16(fast_tanh(acc0[rr]));
                *(unsigned short*)((char*)h2 + (m0 + 16) * 2048 + HSWZ(m0 + 16, n * 2)) = cvt_bf16(fast_tanh(acc1[rr]));
                *(unsigned short*)((char*)h2 + (m0 + 32) * 2048 + HSWZ(m0 + 32, n * 2)) = cvt_bf16(fast_tanh(acc2[rr]));
                *(unsigned short*)((char*)h2 + (m0 + 48) * 2048 + HSWZ(m0 + 48, n * 2)) = cvt_bf16(fast_tanh(acc3v[rr]));
            }
        }
    }
    __syncthreads();

    // ---- layer 3: 1024 -> 1024 via 32x32x16; acc register-resident (64 AGPR). ----
    f32x16 a00, a01, a10, a11;
    {
        float bv0 = b3[wave * 64 + (lane & 31)];
        float bv1 = b3[wave * 64 + 32 + (lane & 31)];
        #pragma unroll
        for (int i = 0; i < 16; ++i) { a00[i] = bv0; a10[i] = bv0; a01[i] = bv1; a11[i] = bv1; }
    }
    const int r0 = lane & 31, r1 = 32 + (lane & 31);
    {
        const unsigned short* bbase = &W3p[((size_t)(wave * 2) * 64) * 512 + lane * 8];
        #pragma unroll 2
        for (int kt = 0; kt < 64; ++kt) {
            bf16x8 A0 = *(const bf16x8*)((const char*)h2 + r0 * 2048 + HSWZ(r0, kt * 32 + kb32));
            bf16x8 A1 = *(const bf16x8*)((const char*)h2 + r1 * 2048 + HSWZ(r1, kt * 32 + kb32));
            bf16x8 B0 = *(const bf16x8*)(bbase + (size_t)kt * 512);
            bf16x8 B1 = *(const bf16x8*)(bbase + (size_t)(64 + kt) * 512);
            a00 = __builtin_amdgcn_mfma_f32_32x32x16_bf16(A0, B0, a00, 0, 0, 0);
            a10 = __builtin_amdgcn_mfma_f32_32x32x16_bf16(A1, B0, a10, 0, 0, 0);
            a01 = __builtin_amdgcn_mfma_f32_32x32x16_bf16(A0, B1, a01, 0, 0, 0);
            a11 = __builtin_amdgcn_mfma_f32_32x32x16_bf16(A1, B1, a11, 0, 0, 0);
        }
    }
    __syncthreads();   // all layer-3 reads of h2 complete

    // ---- h3 = tanh(acc3) -> h2 IN PLACE ----
    {
        int c0l = wave * 64 + (lane & 31);
        #pragma unroll
        for (int r = 0; r < 16; ++r) {
            int row = (r & 3) + 8 * (r >> 2) + 4 * (lane >> 5);   // 0..31
            int rowB = row + 32;
            *(unsigned short*)((char*)h2 + row  * 2048 + HSWZ(row,  c0l * 2)) = cvt_bf16(fast_tanh(a00[r]));
            *(unsigned short*)((char*)h2 + rowB * 2048 + HSWZ(rowB, c0l * 2)) = cvt_bf16(fast_tanh(a10[r]));
            *(unsigned short*)((char*)h2 + row  * 2048 + HSWZ(row,  (c0l + 32) * 2)) = cvt_bf16(fast_tanh(a01[r]));
            *(unsigned short*)((char*)h2 + rowB * 2048 + HSWZ(rowB, (c0l + 32) * 2)) = cvt_bf16(fast_tanh(a11[r]));
        }
    }
    __syncthreads();   // h3 ready

    // ---- layer 4: 1024 -> 128 ----
    {
        const int ct = wave & 7, rtp = wave >> 3;
        const int rowA = rtp * 32 + (lane & 15);
        const int rowB = rowA + 16;
        float bv = b4[ct * 16 + (lane & 15)];
        f32x4 acc4a = (f32x4){ bv, bv, bv, bv };
        f32x4 acc4b = acc4a;
        #pragma unroll 4
        for (int k32 = 0; k32 < 32; ++k32) {
            bf16x8 B = *(const bf16x8*)&W4p[((size_t)(ct * 32 + k32)) * 512 + lane * 8];
            bf16x8 aA = *(const bf16x8*)((const char*)h2 + rowA * 2048 + HSWZ(rowA, k32 * 64 + kb16));
            bf16x8 aB = *(const bf16x8*)((const char*)h2 + rowB * 2048 + HSWZ(rowB, k32 * 64 + kb16));
            acc4a = __builtin_amdgcn_mfma_f32_16x16x32_bf16(aA, B, acc4a, 0, 0, 0);
            acc4b = __builtin_amdgcn_mfma_f32_16x16x32_bf16(aB, B, acc4b, 0, 0, 0);
        }
        // h4 -> hc
        int n = ct * 16 + (lane & 15);
        #pragma unroll
        for (int rr = 0; rr < 4; ++rr) {
            int mA = rtp * 32 + (lane >> 4) * 4 + rr;
            int mB = mA + 16;
            *(unsigned short*)((char*)hc + mA * 256 + HSWZ(mA, n * 2)) = cvt_bf16(fast_tanh(acc4a[rr]));
            *(unsigned short*)((char*)hc + mB * 256 + HSWZ(mB, n * 2)) = cvt_bf16(fast_tanh(acc4b[rr]));
        }
    }
    __syncthreads();

    // ---- layer 5: values = h4 @ W5 + b5 (h2 free -> vbuf) ----
    float* vbuf = (float*)&h2[0];
    {
        int r = t >> 4, g = t & 15;
        float part = 0.0f;
        #pragma unroll
        for (int j = 0; j < 8; ++j) {
            int cidx = g * 8 + j;
            unsigned short hb = *(const unsigned short*)((const char*)hc + r * 256 + HSWZ(r, cidx * 2));
            part += bf2f(hb) * W5[cidx];
        }
        part += __shfl_down(part, 8);
        part += __shfl_down(part, 4);
        part += __shfl_down(part, 2);
        part += __shfl_down(part, 1);
        if (g == 0) {
            float val = part + b5[0];
            values[p0 + r] = val;
            vbuf[r] = val;
        }
    }
    __syncthreads();

    // ---- fused scan: default argmax-gather + worklist emission (wave 0) ----
    if (t < 64) {
        float myv = vbuf[t];
        float v = myv; int idx = t;
        #pragma unroll
        for (int off = 32; off; off >>= 1) {
            float ov = __shfl_down(v, off);
            int oi = __shfl_down(idx, off);
            if (ov > v || (ov == v && oi < idx)) { v = ov; idx = oi; }
        }
        float vm = __shfl(v, 0);
        int best = __shfl(idx, 0);
        if (t < 4) out_actions[blockIdx.x * 4 + t] = actions[best * 4 + t];
        unsigned long long mask = __ballot(myv >= vm - DELTA);
        int nc = __popcll(mask);
        if (nc > 1) {
            unsigned base = 0;
            if (t == 0) base = atomicAdd(&cnts[1], (unsigned)nc);
            base = (unsigned)__shfl((int)base, 0);
            if (base + (unsigned)nc <= (unsigned)ITEM_CAP) {
                if (t == 0) {
                    unsigned slot = atomicAdd(&cnts[0], 1u);
                    wl[slot].s = blockIdx.x; wl[slot].base = base; wl[slot].nc = (unsigned)nc;
                }
                if (myv >= vm - DELTA) {
                    int rank = __popcll(mask & ((1ull << t) - 1ull));
                    items[base + rank] = ((unsigned)blockIdx.x << 6) | (unsigned)t;
                }
            }
        }
    }
}

// ---------------- exact evaluator: 8 flat (state,action) items per batch ----------------
__global__ __launch_bounds__(256) void fixup_eval(
    const float* __restrict__ x, const float* __restrict__ actions,
    const float* __restrict__ W1, const float* __restrict__ b1,
    const float* __restrict__ W2, const float* __restrict__ b2,
    const float* __restrict__ W3, const float* __restrict__ b3,
    const float* __restrict__ W4, const float* __restrict__ b4,
    const float* __restrict__ W5, const float* __restrict__ b5,
    const unsigned* __restrict__ cnts, const unsigned* __restrict__ items,
    float* __restrict__ vexact)
{
    __shared__ float h1s[8][128];
    __shared__ float h2s[8][1024];
    __shared__ float h3s[8][1024];
    __shared__ float h4s[8][128];
    __shared__ float xin[8][5];
    __shared__ float ain[8][4];

    const int t = threadIdx.x;
    int n = (int)cnts[1]; if (n > ITEM_CAP) n = ITEM_CAP;
    int nb = (n + 7) >> 3;
    for (int b = blockIdx.x; b < nb; b += gridDim.x) {
        if (t < 8) {
            int idx = b * 8 + t;
            unsigned it = items[(idx < n) ? idx : (b * 8)];
            int s = (int)((it >> 6) & 2047), a = (int)(it & 63);
            #pragma unroll
            for (int k = 0; k < 5; ++k) xin[t][k] = x[s * 5 + k];
            #pragma unroll
            for (int k = 0; k < 4; ++k) ain[t][k] = actions[a * 4 + k];
        }
        __syncthreads();
        // L1: 9 -> 128
        {
            int r = t >> 5, cb = (t & 31) * 4;
            #pragma unroll
            for (int j = 0; j < 4; ++j) {
                int c = cb + j;
                float acc = b1[c];
                #pragma unroll
                for (int k = 0; k < 5; ++k) acc += xin[r][k] * W1[k * 128 + c];
                #pragma unroll
                for (int k = 0; k < 4; ++k) acc += ain[r][k] * W1[(5 + k) * 128 + c];
                h1s[r][c] = tanhf(acc);
            }
        }
        __syncthreads();
        // L2: 128 -> 1024
        {
            int cb = t * 4;
            float acc[8][4];
            float4 bv = *(const float4*)&b2[cb];
            #pragma unroll
            for (int r = 0; r < 8; ++r) { acc[r][0]=bv.x; acc[r][1]=bv.y; acc[r][2]=bv.z; acc[r][3]=bv.w; }
            for (int k = 0; k < 128; ++k) {
                float4 w = *(const float4*)&W2[k * 1024 + cb];
                #pragma unroll
                for (int r = 0; r < 8; ++r) {
                    float hv = h1s[r][k];
                    acc[r][0] += hv * w.x; acc[r][1] += hv * w.y;
                    acc[r][2] += hv * w.z; acc[r][3] += hv * w.w;
                }
            }
            #pragma unroll
            for (int r = 0; r < 8; ++r) {
                h2s[r][cb+0] = tanhf(acc[r][0]); h2s[r][cb+1] = tanhf(acc[r][1]);
                h2s[r][cb+2] = tanhf(acc[r][2]); h2s[r][cb+3] = tanhf(acc[r][3]);
            }
        }
        __syncthreads();
        // L3: 1024 -> 1024
        {
            int cb = t * 4;
            float acc[8][4];
            float4 bv = *(const float4*)&b3[cb];
            #pragma unroll
            for (int r = 0; r < 8; ++r) { acc[r][0]=bv.x; acc[r][1]=bv.y; acc[r][2]=bv.z; acc[r][3]=bv.w; }
            for (int k = 0; k < 1024; ++k) {
                float4 w = *(const float4*)&W3[k * 1024 + cb];
                #pragma unroll
                for (int r = 0; r < 8; ++r) {
                    float hv = h2s[r][k];
                    acc[r][0] += hv * w.x; acc[r][1] += hv * w.y;
                    acc[r][2] += hv * w.z; acc[r][3] += hv * w.w;
                }
            }
            #pragma unroll
            for (int r = 0; r < 8; ++r) {
                h3s[r][cb+0] = tanhf(acc[r][0]); h3s[r][cb+1] = tanhf(acc[r][1]);
                h3s[r][cb+2] = tanhf(acc[r][2]); h3s[r][cb+3] = tanhf(acc[r][3]);
            }
        }
        __syncthreads();
        // L4: 1024 -> 128
        {
            int r = t >> 5, cb = (t & 31) * 4;
            float acc[4];
            float4 bv = *(const float4*)&b4[cb];
            acc[0]=bv.x; acc[1]=bv.y; acc[2]=bv.z; acc[3]=bv.w;
            for (int k = 0; k < 1024; ++k) {
                float4 w = *(const float4*)&W4[k * 128 + cb];
                float hv = h3s[r][k];
                acc[0] += hv * w.x; acc[1] += hv * w.y; acc[2] += hv * w.z; acc[3] += hv * w.w;
            }
            h4s[r][cb+0] = tanhf(acc[0]); h4s[r][cb+1] = tanhf(acc[1]);
            h4s[r][cb+2] = tanhf(acc[2]); h4s[r][cb+3] = tanhf(acc[3]);
        }
        __syncthreads();
        // L5 -> vexact
        if (t < 8) {
            float acc = b5[0];
            for (int k = 0; k < 128; ++k) acc += h4s[t][k] * W5[k];
            int idx = b * 8 + t;
            if (idx < n) vexact[idx] = acc;
        }
        __syncthreads();
    }
}

// ---------------- final per-state first-max over exact candidate values ----------------
__global__ __launch_bounds__(256) void finalize_argmax(
    const unsigned* __restrict__ cnts, const WLE* __restrict__ wl,
    const unsigned* __restrict__ items, const float* __restrict__ vexact,
    const float* __restrict__ actions, float* __restrict__ out_actions)
{
    int gw = (blockIdx.x * 256 + threadIdx.x) >> 6;
    int lane = threadIdx.x & 63;
    int nwl = (int)cnts[0]; if (nwl > 2048) nwl = 2048;
    if (gw >= nwl) return;
    unsigned s = wl[gw].s, base = wl[gw].base, nc = wl[gw].nc;
    float v = (lane < (int)nc) ? vexact[base + lane] : -3.0e38f;
    int idx = lane;
    #pragma unroll
    for (int off = 32; off; off >>= 1) {
        float ov = __shfl_down(v, off);
        int oi = __shfl_down(idx, off);
        if (ov > v || (ov == v && oi < idx)) { v = ov; idx = oi; }
    }
    int i0 = __shfl(idx, 0);   // items ascend in action order -> first-max
    int a = (int)(items[base + i0] & 63);
    if (lane < 4) out_actions[s * 4 + lane] = actions[a * 4 + lane];
}

// ---------------- fp32 fallback (ws too small) ----------------
#define TR 16
__global__ __launch_bounds__(256) void qnet_fused(
    const float* __restrict__ x, const float* __restrict__ actions,
    const float* __restrict__ W1, const float* __restrict__ b1,
    const float* __restrict__ W2, const float* __restrict__ b2,
    const float* __restrict__ W3, const float* __restrict__ b3,
    const float* __restrict__ W4, const float* __restrict__ b4,
    const float* __restrict__ W5, const float* __restrict__ b5,
    float* __restrict__ values)
{
    __shared__ float h_small[TR][128];
    __shared__ float hA[TR][1024];
    __shared__ float hB[TR][1024];
    const int t = threadIdx.x;
    const int p0 = blockIdx.x * TR;
    for (int i = t; i < TR * 128; i += 256) {
        int r = i >> 7, c = i & 127;
        int p = p0 + r;
        int bidx = p >> 6, aidx = p & 63;
        float acc = b1[c];
        for (int k = 0; k < 5; ++k) acc += x[bidx * 5 + k] * W1[k * 128 + c];
        for (int k = 0; k < 4; ++k) acc += actions[aidx * 4 + k] * W1[(5 + k) * 128 + c];
        h_small[r][c] = tanhf(acc);
    }
    __syncthreads();
    {
        const int c0 = t * 4;
        float4 bias = *(const float4*)&b2[c0];
        float acc[TR][4];
        for (int r = 0; r < TR; ++r) { acc[r][0]=bias.x; acc[r][1]=bias.y; acc[r][2]=bias.z; acc[r][3]=bias.w; }
        for (int k = 0; k < 128; k += 4) {
            float4 w0 = *(const float4*)&W2[(k+0)*1024+c0];
            float4 w1 = *(const float4*)&W2[(k+1)*1024+c0];
            float4 w2 = *(const float4*)&W2[(k+2)*1024+c0];
            float4 w3 = *(const float4*)&W2[(k+3)*1024+c0];
            for (int r = 0; r < TR; ++r) {
                float4 hv = *(const float4*)&h_small[r][k];
                acc[r][0] += hv.x*w0.x + hv.y*w1.x + hv.z*w2.x + hv.w*w3.x;
                acc[r][1] += hv.x*w0.y + hv.y*w1.y + hv.z*w2.y + hv.w*w3.y;
                acc[r][2] += hv.x*w0.z + hv.y*w1.z + hv.z*w2.z + hv.w*w3.z;
                acc[r][3] += hv.x*w0.w + hv.y*w1.w + hv.z*w2.w + hv.w*w3.w;
            }
        }
        for (int r = 0; r < TR; ++r) {
            hA[r][c0+0]=tanhf(acc[r][0]); hA[r][c0+1]=tanhf(acc[r][1]);
            hA[r][c0+2]=tanhf(acc[r][2]); hA[r][c0+3]=tanhf(acc[r][3]);
        }
    }
    __syncthreads();
    {
        const int c0 = t * 4;
        float4 bias = *(const float4*)&b3[c0];
        float acc[TR][4];
        for (int r = 0; r < TR; ++r) { acc[r][0]=bias.x; acc[r][1]=bias.y; acc[r][2]=bias.z; acc[r][3]=bias.w; }
        for (int k = 0; k < 1024; k += 4) {
            float4 w0 = *(const float4*)&W3[(k+0)*1024+c0];
            float4 w1 = *(const float4*)&W3[(k+1)*1024+c0];
            float4 w2 = *(const float4*)&W3[(k+2)*1024+c0];
            float4 w3 = *(const float4*)&W3[(k+3)*1024+c0];
            for (int r = 0; r < TR; ++r) {
                float4 hv = *(const float4*)&hA[r][k];
                acc[r][0] += hv.x*w0.x + hv.y*w1.x + hv.z*w2.x + hv.w*w3.x;
                acc[r][1] += hv.x*w0.y + hv.y*w1.y + hv.z*w2.y + hv.w*w3.y;
                acc[r][2] += hv.x*w0.z + hv.y*w1.z + hv.z*w2.z + hv.w*w3.z;
                acc[r][3] += hv.x*w0.w + hv.y*w1.w + hv.z*w2.w + hv.w*w3.w;
            }
        }
        for (int r = 0; r < TR; ++r) {
            hB[r][c0+0]=tanhf(acc[r][0]); hB[r][c0+1]=tanhf(acc[r][1]);
            hB[r][c0+2]=tanhf(acc[r][2]); hB[r][c0+3]=tanhf(acc[r][3]);
        }
    }
    __syncthreads();
    {
        const int c = t & 127;
        const int rh = t >> 7;
        float acc[8];
        float bias = b4[c];
        for (int r = 0; r < 8; ++r) acc[r] = bias;
        for (int k = 0; k < 1024; k += 4) {
            float w0 = W4[(k+0)*128+c], w1 = W4[(k+1)*128+c];
            float w2 = W4[(k+2)*128+c], w3 = W4[(k+3)*128+c];
            for (int r = 0; r < 8; ++r) {
                float4 hv = *(const float4*)&hB[rh*8+r][k];
                acc[r] += hv.x*w0 + hv.y*w1 + hv.z*w2 + hv.w*w3;
            }
        }
        for (int r = 0; r < 8; ++r) h_small[rh*8+r][c] = tanhf(acc[r]);
    }
    __syncthreads();
    if (t < TR) {
        float acc = b5[0];
        for (int k = 0; k < 128; k += 4) {
            float4 hv = *(const float4*)&h_small[t][k];
            float4 wv = *(const float4*)&W5[k];
            acc += hv.x*wv.x + hv.y*wv.y + hv.z*wv.z + hv.w*wv.w;
        }
        values[p0 + t] = acc;
    }
}

__global__ __launch_bounds__(256) void argmax_gather(
    const float* __restrict__ values, const float* __restrict__ actions,
    float* __restrict__ out_actions)
{
    const int wave = threadIdx.x >> 6;
    const int lane = threadIdx.x & 63;
    const int state = blockIdx.x * (blockDim.x >> 6) + wave;
    float v = values[state * 64 + lane];
    int idx = lane;
    for (int off = 32; off; off >>= 1) {
        float ov = __shfl_down(v, off);
        int oi = __shfl_down(idx, off);
        if (ov > v || (ov == v && oi < idx)) { v = ov; idx = oi; }
    }
    idx = __shfl(idx, 0);
    if (lane < 4) out_actions[state * 4 + lane] = actions[idx * 4 + lane];
}

// ---------------- launcher ----------------
extern "C" void kernel_launch(void* const* d_in, const int* in_sizes, int n_in,
                              void* d_out, int out_size, void* d_ws, size_t ws_size,
                              hipStream_t stream) {
    const float* x       = (const float*)d_in[0];
    const float* actions = (const float*)d_in[1];
    const float* W1 = (const float*)d_in[2];  const float* b1 = (const float*)d_in[3];
    const float* W2 = (const float*)d_in[4];  const float* b2 = (const float*)d_in[5];
    const float* W3 = (const float*)d_in[6];  const float* b3 = (const float*)d_in[7];
    const float* W4 = (const float*)d_in[8];  const float* b4 = (const float*)d_in[9];
    const float* W5 = (const float*)d_in[10]; const float* b5 = (const float*)d_in[11];

    float* out_actions = (float*)d_out;              // [2048,4]
    float* values      = (float*)d_out + 2048 * 4;   // [2048,64]

    const size_t nW2 = 128 * 1024, nW3 = 1024 * 1024, nW4 = 1024 * 128;
    const size_t wbytes = (nW2 + nW3 + nW4) * sizeof(unsigned short);   // 2621440
    const size_t need = wbytes + 16 + 2048 * sizeof(WLE) + ITEM_CAP * 4 + ITEM_CAP * 4;

    if (ws_size >= need) {
        unsigned short* W2p = (unsigned short*)d_ws;
        unsigned short* W3p = W2p + nW2;
        unsigned short* W4p = W3p + nW3;
        char* p = (char*)d_ws + wbytes;
        unsigned* cnts = (unsigned*)p;                 p += 16;
        WLE* wl = (WLE*)p;                             p += 2048 * sizeof(WLE);
        unsigned* items = (unsigned*)p;                p += ITEM_CAP * 4;
        float* vexact = (float*)p;

        pack_all<<<640, 256, 0, stream>>>(W2, W3, W4, W2p, W3p, W4p, cnts);
        qnet_mfma<<<2048, 1024, 0, stream>>>(x, actions, W1, b1, b2, b3, b4, W5, b5,
                                             W2p, W3p, W4p, values, out_actions,
                                             cnts, wl, items);
        fixup_eval<<<512, 256, 0, stream>>>(x, actions, W1, b1, W2, b2, W3, b3,
                                            W4, b4, W5, b5, cnts, items, vexact);
        finalize_argmax<<<512, 256, 0, stream>>>(cnts, wl, items, vexact,
                                                 actions, out_actions);
    } else {
        qnet_fused<<<2048 * 64 / TR, 256, 0, stream>>>(x, actions, W1, b1, W2, b2, W3, b3,
                                                       W4, b4, W5, b5, values);
        argmax_gather<<<2048 / 4, 256, 0, stream>>>(values, actions, out_actions);
    }
}